// Round 2
// baseline (626.601 us; speedup 1.0000x reference)
//
#include <hip/hip_runtime.h>
#include <hip/hip_bf16.h>
#include <cstdint>

#define HIDDEN 1024
#define HEADS 16
#define HDIM 64
#define BATCH 4
#define SEQ 2048
#define MTOT (BATCH * SEQ)   // 8192

typedef __attribute__((ext_vector_type(8))) short bfrag;   // 8 bf16 (A/B frag)
typedef __attribute__((ext_vector_type(4))) short bhalf;   // 4 bf16
typedef __attribute__((ext_vector_type(4))) float cfrag;   // 4 f32 (C/D frag)
typedef __attribute__((ext_vector_type(4))) float float4v;
typedef __attribute__((ext_vector_type(4))) unsigned short ushort4v;

#define AS1 __attribute__((address_space(1)))
#define AS3 __attribute__((address_space(3)))

__device__ __forceinline__ void gl_lds16(const void* g, void* l) {
  // async global->LDS, 16B per lane; LDS dest = wave-uniform base + lane*16
  __builtin_amdgcn_global_load_lds((AS1 void*)g, (AS3 void*)l, 16, 0, 0);
}

__device__ __forceinline__ uint16_t f2b(float f) {  // f32 -> bf16 bits, RNE
  union { float f; uint32_t u; } v; v.f = f;
  uint32_t u = v.u;
  return (uint16_t)((u + 0x7FFFu + ((u >> 16) & 1u)) >> 16);
}

// ---------------- kernel 1: x fp32 -> bf16 ----------------
__global__ __launch_bounds__(256) void cvt_x_kernel(const float* __restrict__ in,
                                                    uint16_t* __restrict__ out, int n8) {
  int i = blockIdx.x * blockDim.x + threadIdx.x;
  if (i >= n8) return;
  float4v a = ((const float4v*)in)[2 * i];
  float4v b = ((const float4v*)in)[2 * i + 1];
  bfrag o;
  o[0] = (short)f2b(a[0]); o[1] = (short)f2b(a[1]);
  o[2] = (short)f2b(a[2]); o[3] = (short)f2b(a[3]);
  o[4] = (short)f2b(b[0]); o[5] = (short)f2b(b[1]);
  o[6] = (short)f2b(b[2]); o[7] = (short)f2b(b[3]);
  ((bfrag*)out)[i] = o;
}

// ---------------- kernel 2: W [K][N] fp32 -> Wt [N][K] bf16 (x3) ----------------
__global__ __launch_bounds__(256) void cvt_w_kernel(const float* __restrict__ W0,
                                                    const float* __restrict__ W1,
                                                    const float* __restrict__ W2,
                                                    uint16_t* __restrict__ Wt) {
  const float* W = blockIdx.z == 0 ? W0 : (blockIdx.z == 1 ? W1 : W2);
  uint16_t* out = Wt + (size_t)blockIdx.z * HIDDEN * HIDDEN;
  __shared__ float tile[64][65];
  int n0 = blockIdx.x * 64, k0 = blockIdx.y * 64;
  int t = threadIdx.x;
  int r = t >> 2, cq = (t & 3) * 16;
#pragma unroll
  for (int i = 0; i < 16; i += 4) {
    float4v v = *(const float4v*)&W[(size_t)(k0 + r) * HIDDEN + n0 + cq + i];
    tile[r][cq + i + 0] = v[0]; tile[r][cq + i + 1] = v[1];
    tile[r][cq + i + 2] = v[2]; tile[r][cq + i + 3] = v[3];
  }
  __syncthreads();
  bfrag o0, o1;
#pragma unroll
  for (int i = 0; i < 8; ++i) o0[i] = (short)f2b(tile[cq + i][r]);
#pragma unroll
  for (int i = 0; i < 8; ++i) o1[i] = (short)f2b(tile[cq + 8 + i][r]);
  *(bfrag*)&out[(size_t)(n0 + r) * HIDDEN + k0 + cq] = o0;
  *(bfrag*)&out[(size_t)(n0 + r) * HIDDEN + k0 + cq + 8] = o1;
}

// ---------------- kernel 3: QKV projection GEMM (m97 structure) ----------------
// C[m][n] = sum_k X[m][k] * Wt[n][k] + bias[n]
// which==0: Q bf16 [8192][1024], scaled by 0.125 (softmax scale folded in)
// which==1: K bf16 [8192][1024]
// which==2: V^T bf16 [64 bh][64 d][2048 s]
__global__ __launch_bounds__(256) void gemm_qkv_kernel(
    const uint16_t* __restrict__ X, const uint16_t* __restrict__ Wt,
    const float* __restrict__ b0, const float* __restrict__ b1,
    const float* __restrict__ b2,
    uint16_t* __restrict__ Qo, uint16_t* __restrict__ Ko, uint16_t* __restrict__ Vo) {
  __shared__ uint16_t As[128 * 32];
  __shared__ uint16_t Bs[128 * 32];
  int which = blockIdx.z;
  const uint16_t* Wp = Wt + (size_t)which * HIDDEN * HIDDEN;
  const float* bias = which == 0 ? b0 : (which == 1 ? b1 : b2);

  int m0 = blockIdx.x * 128, n0 = blockIdx.y * 128;
  int tid = threadIdx.x;
  int wave = tid >> 6, lane = tid & 63;
  int wm = wave >> 1, wn = wave & 1;       // 2x2 wave grid, 64x64 per wave
  int g = lane >> 4, c = lane & 15;
  int sr = lane >> 2;                       // staging: row within 16-row chunk
  int sc = (lane & 3) * 8;                  // staging: k offset (8 bf16 = 16B)

  cfrag acc[4][4];
#pragma unroll
  for (int i = 0; i < 4; ++i)
#pragma unroll
    for (int j = 0; j < 4; ++j) acc[i][j] = cfrag{0.f, 0.f, 0.f, 0.f};

  for (int kt = 0; kt < HIDDEN / 32; ++kt) {
    int kc = kt * 32 + sc;
#pragma unroll
    for (int i = 0; i < 2; ++i) {
      int rowA = (i * 4 + wave) * 16;  // wave-uniform
      gl_lds16(&X[(size_t)(m0 + rowA + sr) * HIDDEN + kc], &As[rowA * 32]);
      gl_lds16(&Wp[(size_t)(n0 + rowA + sr) * HIDDEN + kc], &Bs[rowA * 32]);
    }
    __syncthreads();  // vmcnt(0) drained before barrier -> LDS ready
    bfrag af[4], bf[4];
#pragma unroll
    for (int mt = 0; mt < 4; ++mt)
      af[mt] = *(const bfrag*)&As[(wm * 64 + mt * 16 + c) * 32 + g * 8];
#pragma unroll
    for (int nt = 0; nt < 4; ++nt)
      bf[nt] = *(const bfrag*)&Bs[(wn * 64 + nt * 16 + c) * 32 + g * 8];
#pragma unroll
    for (int mt = 0; mt < 4; ++mt)
#pragma unroll
      for (int nt = 0; nt < 4; ++nt)
        acc[mt][nt] = __builtin_amdgcn_mfma_f32_16x16x32_bf16(af[mt], bf[nt],
                                                              acc[mt][nt], 0, 0, 0);
    __syncthreads();  // all waves done with LDS before next stage
  }

  if (which == 2) {
    // V^T epilogue: [bh][d][s]; 4 consecutive s per fragment -> ushort4 store
    int bb_ = m0 >> 11;                 // batch (m0 128-aligned, 2048%128==0)
    int s0 = (m0 & 2047) + wm * 64;
#pragma unroll
    for (int nt = 0; nt < 4; ++nt) {
      int n = n0 + wn * 64 + nt * 16 + c;
      int h = n >> 6, d = n & 63;
      float bb = bias[n];
      size_t base = ((size_t)(bb_ * 16 + h) * 64 + d) * SEQ;
#pragma unroll
      for (int mt = 0; mt < 4; ++mt) {
        int s = s0 + mt * 16 + g * 4;
        ushort4v pk;
        pk[0] = f2b(acc[mt][nt][0] + bb);
        pk[1] = f2b(acc[mt][nt][1] + bb);
        pk[2] = f2b(acc[mt][nt][2] + bb);
        pk[3] = f2b(acc[mt][nt][3] + bb);
        *(ushort4v*)&Vo[base + s] = pk;
      }
    }
  } else {
    uint16_t* out = which == 0 ? Qo : Ko;
    float sc_ = which == 0 ? 0.125f : 1.0f;   // softmax 1/sqrt(64) folded into Q
#pragma unroll
    for (int nt = 0; nt < 4; ++nt) {
      int n = n0 + wn * 64 + nt * 16 + c;
      float bb = bias[n];
#pragma unroll
      for (int mt = 0; mt < 4; ++mt) {
        int mb = m0 + wm * 64 + mt * 16 + g * 4;
#pragma unroll
        for (int r = 0; r < 4; ++r)
          out[(size_t)(mb + r) * HIDDEN + n] = f2b((acc[mt][nt][r] + bb) * sc_);
      }
    }
  }
}

// ---------------- kernel 4: flash attention (barrier-free) ----------------
// Q,K bf16 [8192][1024]; VT bf16 [64][64][2048]; out fp32 [8192][1024]
__global__ __launch_bounds__(256) void attn_kernel(
    const uint16_t* __restrict__ Q, const uint16_t* __restrict__ K,
    const uint16_t* __restrict__ VT, float* __restrict__ out) {
  __shared__ uint16_t Pl[4][16][68];     // per-wave P [qrow][kv], stride 68

  // XCD-aware swizzle: each XCD's 256 resident blocks cover 8 heads (KV=4MB=L2)
  int bid = blockIdx.x;
  int wg = (bid & 7) * 256 + (bid >> 3);
  int bh = wg >> 5, qt = wg & 31;
  int b = bh >> 4, h = bh & 15;
  int tid = threadIdx.x, wave = tid >> 6, lane = tid & 63;
  int g = lane >> 4, c = lane & 15;
  size_t rowb = (size_t)b * SEQ;
  int colb = h * HDIM;
  const uint16_t* Kh = K + rowb * HIDDEN + colb;          // [s][d] stride 1024
  const uint16_t* Vh = VT + (size_t)bh * HDIM * SEQ;      // [d][s]

  // Q fragments (A-frag: row = lane&15, k = g*8..g*8+7), held for all kv tiles
  int qrow = qt * 64 + wave * 16 + c;
  bfrag aq[2];
  aq[0] = *(const bfrag*)&Q[(rowb + qrow) * HIDDEN + colb + g * 8];
  aq[1] = *(const bfrag*)&Q[(rowb + qrow) * HIDDEN + colb + 32 + g * 8];

  float mr[4], lr[4];
  cfrag oacc[4];
#pragma unroll
  for (int r = 0; r < 4; ++r) { mr[r] = -INFINITY; lr[r] = 0.f; }
#pragma unroll
  for (int dt = 0; dt < 4; ++dt) oacc[dt] = cfrag{0.f, 0.f, 0.f, 0.f};

  for (int j0 = 0; j0 < SEQ; j0 += 64) {
    // S = Q @ K^T  (K B-frag straight from global; K tile is L2-resident)
    cfrag s[4];
#pragma unroll
    for (int nt = 0; nt < 4; ++nt) s[nt] = cfrag{0.f, 0.f, 0.f, 0.f};
#pragma unroll
    for (int kb = 0; kb < 2; ++kb) {
#pragma unroll
      for (int nt = 0; nt < 4; ++nt) {
        bfrag bk = *(const bfrag*)&Kh[(size_t)(j0 + nt * 16 + c) * HIDDEN +
                                      kb * 32 + g * 8];
        s[nt] = __builtin_amdgcn_mfma_f32_16x16x32_bf16(aq[kb], bk, s[nt], 0, 0, 0);
      }
    }

    // online softmax; row = g*4+r, cols spread over 16-lane group x 4 tiles
#pragma unroll
    for (int r = 0; r < 4; ++r) {
      float s0 = s[0][r], s1 = s[1][r], s2 = s[2][r], s3 = s[3][r];
      float mx = fmaxf(fmaxf(s0, s1), fmaxf(s2, s3));
#pragma unroll
      for (int off = 1; off < 16; off <<= 1)
        mx = fmaxf(mx, __shfl_xor(mx, off, 64));
      float mnew = fmaxf(mr[r], mx);
      float alpha = __expf(mr[r] - mnew);   // exp(-inf)=0 on first tile
      float p0 = __expf(s0 - mnew), p1 = __expf(s1 - mnew),
            p2 = __expf(s2 - mnew), p3 = __expf(s3 - mnew);
      float ps = p0 + p1 + p2 + p3;
#pragma unroll
      for (int off = 1; off < 16; off <<= 1)
        ps += __shfl_xor(ps, off, 64);
      lr[r] = lr[r] * alpha + ps;
      mr[r] = mnew;
#pragma unroll
      for (int dt = 0; dt < 4; ++dt) oacc[dt][r] *= alpha;
      int pr = g * 4 + r;
      Pl[wave][pr][c]      = f2b(p0);
      Pl[wave][pr][16 + c] = f2b(p1);
      Pl[wave][pr][32 + c] = f2b(p2);
      Pl[wave][pr][48 + c] = f2b(p3);
    }
    // in-wave only: make P writes visible before fragment reads (rule #18)
    asm volatile("s_waitcnt lgkmcnt(0)" ::: "memory");
    __builtin_amdgcn_sched_barrier(0);

    // PV: ctx += P @ V  (P A-frag from per-wave LDS; V^T B-frag from global)
#pragma unroll
    for (int kb = 0; kb < 2; ++kb) {
      const uint16_t* pp = &Pl[wave][c][kb * 32 + g * 8];
      bhalf lo = *(const bhalf*)pp;         // stride 68 is 8B-aligned -> 2x b64
      bhalf hi = *(const bhalf*)(pp + 4);
      bfrag ap;
      ap[0] = lo[0]; ap[1] = lo[1]; ap[2] = lo[2]; ap[3] = lo[3];
      ap[4] = hi[0]; ap[5] = hi[1]; ap[6] = hi[2]; ap[7] = hi[3];
#pragma unroll
      for (int dt = 0; dt < 4; ++dt) {
        bfrag bv = *(const bfrag*)&Vh[(size_t)(dt * 16 + c) * SEQ +
                                      j0 + kb * 32 + g * 8];
        oacc[dt] = __builtin_amdgcn_mfma_f32_16x16x32_bf16(ap, bv, oacc[dt], 0, 0, 0);
      }
    }
  }

#pragma unroll
  for (int r = 0; r < 4; ++r) {
    float inv = 1.0f / lr[r];
    size_t orow = rowb + (size_t)qt * 64 + wave * 16 + g * 4 + r;
#pragma unroll
    for (int dt = 0; dt < 4; ++dt)
      out[orow * HIDDEN + colb + dt * 16 + c] = oacc[dt][r] * inv;
  }
}

extern "C" void kernel_launch(void* const* d_in, const int* in_sizes, int n_in,
                              void* d_out, int out_size, void* d_ws, size_t ws_size,
                              hipStream_t stream) {
  const float* x  = (const float*)d_in[0];
  const float* Wq = (const float*)d_in[1];
  const float* bq = (const float*)d_in[2];
  const float* Wk = (const float*)d_in[3];
  const float* bk = (const float*)d_in[4];
  const float* Wv = (const float*)d_in[5];
  const float* bv = (const float*)d_in[6];
  float* out = (float*)d_out;

  uint8_t* ws = (uint8_t*)d_ws;
  const size_t XB = 0;
  const size_t WT = XB + (size_t)MTOT * HIDDEN * 2;        // 16 MB
  const size_t QB = WT + (size_t)3 * HIDDEN * HIDDEN * 2;  // +6 MB
  const size_t KB = QB + (size_t)MTOT * HIDDEN * 2;
  const size_t VB = KB + (size_t)MTOT * HIDDEN * 2;        // total ~70 MB
  uint16_t* Xb = (uint16_t*)(ws + XB);
  uint16_t* Wt = (uint16_t*)(ws + WT);
  uint16_t* Qb = (uint16_t*)(ws + QB);
  uint16_t* Kb = (uint16_t*)(ws + KB);
  uint16_t* Vb = (uint16_t*)(ws + VB);   // V^T [64][64][2048]

  cvt_x_kernel<<<dim3(MTOT * HIDDEN / 8 / 256), 256, 0, stream>>>(x, Xb,
                                                                  MTOT * HIDDEN / 8);
  cvt_w_kernel<<<dim3(16, 16, 3), 256, 0, stream>>>(Wq, Wk, Wv, Wt);
  gemm_qkv_kernel<<<dim3(64, 8, 3), 256, 0, stream>>>(Xb, Wt, bq, bk, bv, Qb, Kb, Vb);
  attn_kernel<<<dim3(2048), 256, 0, stream>>>(Qb, Kb, Vb, out);
}

// Round 3
// 390.968 us; speedup vs baseline: 1.6027x; 1.6027x over previous
//
#include <hip/hip_runtime.h>
#include <hip/hip_bf16.h>
#include <cstdint>

#define HIDDEN 1024
#define HEADS 16
#define HDIM 64
#define BATCH 4
#define SEQ 2048
#define MTOT (BATCH * SEQ)   // 8192

typedef __attribute__((ext_vector_type(8))) short bfrag;   // 8 bf16 (A/B frag)
typedef __attribute__((ext_vector_type(4))) short bhalf;   // 4 bf16
typedef __attribute__((ext_vector_type(4))) float cfrag;   // 4 f32 (C/D frag)
typedef __attribute__((ext_vector_type(4))) float float4v;
typedef __attribute__((ext_vector_type(4))) unsigned short ushort4v;

#define AS1 __attribute__((address_space(1)))
#define AS3 __attribute__((address_space(3)))

__device__ __forceinline__ void gl_lds16(const void* g, void* l) {
  // async global->LDS, 16B per lane; LDS dest = wave-uniform base + lane*16
  __builtin_amdgcn_global_load_lds((AS1 void*)g, (AS3 void*)l, 16, 0, 0);
}

__device__ __forceinline__ uint16_t f2b(float f) {  // f32 -> bf16 bits, RNE
  union { float f; uint32_t u; } v; v.f = f;
  uint32_t u = v.u;
  return (uint16_t)((u + 0x7FFFu + ((u >> 16) & 1u)) >> 16);
}

// ---------------- kernel 1: x fp32 -> bf16 ----------------
__global__ __launch_bounds__(256) void cvt_x_kernel(const float* __restrict__ in,
                                                    uint16_t* __restrict__ out, int n8) {
  int i = blockIdx.x * blockDim.x + threadIdx.x;
  if (i >= n8) return;
  float4v a = ((const float4v*)in)[2 * i];
  float4v b = ((const float4v*)in)[2 * i + 1];
  bfrag o;
  o[0] = (short)f2b(a[0]); o[1] = (short)f2b(a[1]);
  o[2] = (short)f2b(a[2]); o[3] = (short)f2b(a[3]);
  o[4] = (short)f2b(b[0]); o[5] = (short)f2b(b[1]);
  o[6] = (short)f2b(b[2]); o[7] = (short)f2b(b[3]);
  ((bfrag*)out)[i] = o;
}

// ---------------- kernel 2: W [K][N] fp32 -> Wt [N][K] bf16 (x3) ----------------
__global__ __launch_bounds__(256) void cvt_w_kernel(const float* __restrict__ W0,
                                                    const float* __restrict__ W1,
                                                    const float* __restrict__ W2,
                                                    uint16_t* __restrict__ Wt) {
  const float* W = blockIdx.z == 0 ? W0 : (blockIdx.z == 1 ? W1 : W2);
  uint16_t* out = Wt + (size_t)blockIdx.z * HIDDEN * HIDDEN;
  __shared__ float tile[64][65];
  int n0 = blockIdx.x * 64, k0 = blockIdx.y * 64;
  int t = threadIdx.x;
  int r = t >> 2, cq = (t & 3) * 16;
#pragma unroll
  for (int i = 0; i < 16; i += 4) {
    float4v v = *(const float4v*)&W[(size_t)(k0 + r) * HIDDEN + n0 + cq + i];
    tile[r][cq + i + 0] = v[0]; tile[r][cq + i + 1] = v[1];
    tile[r][cq + i + 2] = v[2]; tile[r][cq + i + 3] = v[3];
  }
  __syncthreads();
  bfrag o0, o1;
#pragma unroll
  for (int i = 0; i < 8; ++i) o0[i] = (short)f2b(tile[cq + i][r]);
#pragma unroll
  for (int i = 0; i < 8; ++i) o1[i] = (short)f2b(tile[cq + 8 + i][r]);
  *(bfrag*)&out[(size_t)(n0 + r) * HIDDEN + k0 + cq] = o0;
  *(bfrag*)&out[(size_t)(n0 + r) * HIDDEN + k0 + cq + 8] = o1;
}

// ---------------- kernel 3: QKV projection GEMM (m97 structure) ----------------
// C[m][n] = sum_k X[m][k] * Wt[n][k] + bias[n]
// which==0: Q bf16 [8192][1024], scaled by 0.125 (softmax scale folded in)
// which==1: K bf16 [8192][1024]
// which==2: V^T bf16 [64 bh][64 d][2048 s]
__global__ __launch_bounds__(256) void gemm_qkv_kernel(
    const uint16_t* __restrict__ X, const uint16_t* __restrict__ Wt,
    const float* __restrict__ b0, const float* __restrict__ b1,
    const float* __restrict__ b2,
    uint16_t* __restrict__ Qo, uint16_t* __restrict__ Ko, uint16_t* __restrict__ Vo) {
  __shared__ uint16_t As[128 * 32];
  __shared__ uint16_t Bs[128 * 32];
  int which = blockIdx.z;
  const uint16_t* Wp = Wt + (size_t)which * HIDDEN * HIDDEN;
  const float* bias = which == 0 ? b0 : (which == 1 ? b1 : b2);

  int m0 = blockIdx.x * 128, n0 = blockIdx.y * 128;
  int tid = threadIdx.x;
  int wave = tid >> 6, lane = tid & 63;
  int wm = wave >> 1, wn = wave & 1;       // 2x2 wave grid, 64x64 per wave
  int g = lane >> 4, c = lane & 15;
  int sr = lane >> 2;                       // staging: row within 16-row chunk
  int sc = (lane & 3) * 8;                  // staging: k offset (8 bf16 = 16B)

  cfrag acc[4][4];
#pragma unroll
  for (int i = 0; i < 4; ++i)
#pragma unroll
    for (int j = 0; j < 4; ++j) acc[i][j] = cfrag{0.f, 0.f, 0.f, 0.f};

  for (int kt = 0; kt < HIDDEN / 32; ++kt) {
    int kc = kt * 32 + sc;
#pragma unroll
    for (int i = 0; i < 2; ++i) {
      int rowA = (i * 4 + wave) * 16;  // wave-uniform
      gl_lds16(&X[(size_t)(m0 + rowA + sr) * HIDDEN + kc], &As[rowA * 32]);
      gl_lds16(&Wp[(size_t)(n0 + rowA + sr) * HIDDEN + kc], &Bs[rowA * 32]);
    }
    __syncthreads();  // vmcnt(0) drained before barrier -> LDS ready
    bfrag af[4], bf[4];
#pragma unroll
    for (int mt = 0; mt < 4; ++mt)
      af[mt] = *(const bfrag*)&As[(wm * 64 + mt * 16 + c) * 32 + g * 8];
#pragma unroll
    for (int nt = 0; nt < 4; ++nt)
      bf[nt] = *(const bfrag*)&Bs[(wn * 64 + nt * 16 + c) * 32 + g * 8];
#pragma unroll
    for (int mt = 0; mt < 4; ++mt)
#pragma unroll
      for (int nt = 0; nt < 4; ++nt)
        acc[mt][nt] = __builtin_amdgcn_mfma_f32_16x16x32_bf16(af[mt], bf[nt],
                                                              acc[mt][nt], 0, 0, 0);
    __syncthreads();  // all waves done with LDS before next stage
  }

  if (which == 2) {
    // V^T epilogue: [bh][d][s]; 4 consecutive s per fragment -> ushort4 store
    int bb_ = m0 >> 11;                 // batch (m0 128-aligned, 2048%128==0)
    int s0 = (m0 & 2047) + wm * 64;
#pragma unroll
    for (int nt = 0; nt < 4; ++nt) {
      int n = n0 + wn * 64 + nt * 16 + c;
      int h = n >> 6, d = n & 63;
      float bb = bias[n];
      size_t base = ((size_t)(bb_ * 16 + h) * 64 + d) * SEQ;
#pragma unroll
      for (int mt = 0; mt < 4; ++mt) {
        int s = s0 + mt * 16 + g * 4;
        ushort4v pk;
        pk[0] = f2b(acc[mt][nt][0] + bb);
        pk[1] = f2b(acc[mt][nt][1] + bb);
        pk[2] = f2b(acc[mt][nt][2] + bb);
        pk[3] = f2b(acc[mt][nt][3] + bb);
        *(ushort4v*)&Vo[base + s] = pk;
      }
    }
  } else {
    uint16_t* out = which == 0 ? Qo : Ko;
    float sc_ = which == 0 ? 0.125f : 1.0f;   // softmax 1/sqrt(64) folded into Q
#pragma unroll
    for (int nt = 0; nt < 4; ++nt) {
      int n = n0 + wn * 64 + nt * 16 + c;
      float bb = bias[n];
#pragma unroll
      for (int mt = 0; mt < 4; ++mt) {
        int mb = m0 + wm * 64 + mt * 16 + g * 4;
#pragma unroll
        for (int r = 0; r < 4; ++r)
          out[(size_t)(mb + r) * HIDDEN + n] = f2b((acc[mt][nt][r] + bb) * sc_);
      }
    }
  }
}

// ---------------- kernel 4: flash attention (LDS-staged, dbuf, swizzled) ----------------
// Q,K bf16 [8192][1024]; VT bf16 [64][64][2048]; out fp32 [8192][1024]
__global__ __launch_bounds__(256) void attn_kernel(
    const uint16_t* __restrict__ Q, const uint16_t* __restrict__ K,
    const uint16_t* __restrict__ VT, float* __restrict__ out) {
  __shared__ uint16_t Ks[2][64 * 64];    // K tile, XOR-swizzled content
  __shared__ uint16_t Vs[2][64 * 64];    // V^T tile [d][s], XOR-swizzled content
  __shared__ uint16_t Pl[4][16][68];     // per-wave P [qrow][kv], stride 68

  // XCD-aware swizzle: each XCD's resident blocks cover 8 heads (KV=4MB=L2)
  int bid = blockIdx.x;
  int wg = (bid & 7) * 256 + (bid >> 3);
  int bh = wg >> 5, qt = wg & 31;
  int b = bh >> 4, h = bh & 15;
  int tid = threadIdx.x, wave = tid >> 6, lane = tid & 63;
  int g = lane >> 4, c = lane & 15;
  size_t rowb = (size_t)b * SEQ;
  int colb = h * HDIM;
  const uint16_t* Kh = K + rowb * HIDDEN + colb;          // [s][d] stride 1024
  const uint16_t* Vh = VT + (size_t)bh * HDIM * SEQ;      // [d][s] stride 2048

  // staging geometry: lane covers 16B; pre-swizzled global col so that the
  // LINEAR global_load_lds write lands XOR-swizzled (rule #21 both-sides)
  int r8 = lane >> 3, c8 = lane & 7;
  int scol = ((c8 ^ r8) << 3);           // element offset 0..56
  int sbrow = (wave & 1) * 32;           // this wave's 4 calls start here

  // Q fragments (A-frag: row = lane&15, k = g*8..g*8+7), held for all kv tiles
  int qrow = qt * 64 + wave * 16 + c;
  bfrag aq[2];
  aq[0] = *(const bfrag*)&Q[(rowb + qrow) * HIDDEN + colb + g * 8];
  aq[1] = *(const bfrag*)&Q[(rowb + qrow) * HIDDEN + colb + 32 + g * 8];

  float mr[4], lr[4];
  cfrag oacc[4];
#pragma unroll
  for (int r = 0; r < 4; ++r) { mr[r] = -INFINITY; lr[r] = 0.f; }
#pragma unroll
  for (int dt = 0; dt < 4; ++dt) oacc[dt] = cfrag{0.f, 0.f, 0.f, 0.f};

  // prologue: stage tile 0 into buf 0 (waves 0-1: K rows, waves 2-3: V rows)
  {
    if (wave < 2) {
#pragma unroll
      for (int j = 0; j < 4; ++j) {
        int rl = sbrow + j * 8;
        gl_lds16(&Kh[(size_t)(rl + r8) * HIDDEN + scol], &Ks[0][rl * 64]);
      }
    } else {
#pragma unroll
      for (int j = 0; j < 4; ++j) {
        int rl = sbrow + j * 8;
        gl_lds16(&Vh[(size_t)(rl + r8) * SEQ + scol], &Vs[0][rl * 64]);
      }
    }
  }
  __syncthreads();  // compiler drains vmcnt before barrier -> tile 0 ready

  int cur = 0;
  int sw = (c & 7) << 4;                 // read-side byte swizzle

  for (int t = 0; t < 32; ++t) {
    int j0 = t * 64;
    // issue next-tile stage first; latency hides under this tile's compute
    if (t < 31) {
      int jn = j0 + 64;
      if (wave < 2) {
#pragma unroll
        for (int j = 0; j < 4; ++j) {
          int rl = sbrow + j * 8;
          gl_lds16(&Kh[(size_t)(jn + rl + r8) * HIDDEN + scol],
                   &Ks[cur ^ 1][rl * 64]);
        }
      } else {
#pragma unroll
        for (int j = 0; j < 4; ++j) {
          int rl = sbrow + j * 8;
          gl_lds16(&Vh[(size_t)(rl + r8) * SEQ + jn + scol],
                   &Vs[cur ^ 1][rl * 64]);
        }
      }
    }

    const uint8_t* Kbuf = (const uint8_t*)Ks[cur];
    const uint8_t* Vbuf = (const uint8_t*)Vs[cur];

    // S = Q @ K^T from swizzled LDS
    cfrag s[4];
#pragma unroll
    for (int nt = 0; nt < 4; ++nt) s[nt] = cfrag{0.f, 0.f, 0.f, 0.f};
    __builtin_amdgcn_s_setprio(1);
#pragma unroll
    for (int kb = 0; kb < 2; ++kb) {
#pragma unroll
      for (int nt = 0; nt < 4; ++nt) {
        int off = ((nt * 16 + c) * 128 + kb * 64 + g * 16) ^ sw;
        bfrag bk = *(const bfrag*)(Kbuf + off);
        s[nt] = __builtin_amdgcn_mfma_f32_16x16x32_bf16(aq[kb], bk, s[nt], 0, 0, 0);
      }
    }
    __builtin_amdgcn_s_setprio(0);

    // online softmax; row = g*4+r, cols spread over 16-lane group x 4 tiles
#pragma unroll
    for (int r = 0; r < 4; ++r) {
      float s0 = s[0][r], s1 = s[1][r], s2 = s[2][r], s3 = s[3][r];
      float mx = fmaxf(fmaxf(s0, s1), fmaxf(s2, s3));
#pragma unroll
      for (int off = 1; off < 16; off <<= 1)
        mx = fmaxf(mx, __shfl_xor(mx, off, 64));
      float mnew = fmaxf(mr[r], mx);
      float alpha = __expf(mr[r] - mnew);   // exp(-inf)=0 on first tile
      float p0 = __expf(s0 - mnew), p1 = __expf(s1 - mnew),
            p2 = __expf(s2 - mnew), p3 = __expf(s3 - mnew);
      float ps = p0 + p1 + p2 + p3;
#pragma unroll
      for (int off = 1; off < 16; off <<= 1)
        ps += __shfl_xor(ps, off, 64);
      lr[r] = lr[r] * alpha + ps;
      mr[r] = mnew;
#pragma unroll
      for (int dt = 0; dt < 4; ++dt) oacc[dt][r] *= alpha;
      int pr = g * 4 + r;
      Pl[wave][pr][c]      = f2b(p0);
      Pl[wave][pr][16 + c] = f2b(p1);
      Pl[wave][pr][32 + c] = f2b(p2);
      Pl[wave][pr][48 + c] = f2b(p3);
    }
    // in-wave only: make P writes visible before fragment reads (rule #18)
    asm volatile("s_waitcnt lgkmcnt(0)" ::: "memory");
    __builtin_amdgcn_sched_barrier(0);

    // PV: ctx += P @ V from swizzled LDS
    __builtin_amdgcn_s_setprio(1);
#pragma unroll
    for (int kb = 0; kb < 2; ++kb) {
      const uint16_t* pp = &Pl[wave][c][kb * 32 + g * 8];
      bhalf lo = *(const bhalf*)pp;         // stride 68 is 8B-aligned -> 2x b64
      bhalf hi = *(const bhalf*)(pp + 4);
      bfrag ap;
      ap[0] = lo[0]; ap[1] = lo[1]; ap[2] = lo[2]; ap[3] = lo[3];
      ap[4] = hi[0]; ap[5] = hi[1]; ap[6] = hi[2]; ap[7] = hi[3];
#pragma unroll
      for (int dt = 0; dt < 4; ++dt) {
        int off = ((dt * 16 + c) * 128 + kb * 64 + g * 16) ^ sw;
        bfrag bv = *(const bfrag*)(Vbuf + off);
        oacc[dt] = __builtin_amdgcn_mfma_f32_16x16x32_bf16(ap, bv, oacc[dt], 0, 0, 0);
      }
    }
    __builtin_amdgcn_s_setprio(0);

    __syncthreads();  // drains this wave's stage vmcnt; next tile ready
    cur ^= 1;
  }

#pragma unroll
  for (int r = 0; r < 4; ++r) {
    float inv = 1.0f / lr[r];
    size_t orow = rowb + (size_t)qt * 64 + wave * 16 + g * 4 + r;
#pragma unroll
    for (int dt = 0; dt < 4; ++dt)
      out[orow * HIDDEN + colb + dt * 16 + c] = oacc[dt][r] * inv;
  }
}

extern "C" void kernel_launch(void* const* d_in, const int* in_sizes, int n_in,
                              void* d_out, int out_size, void* d_ws, size_t ws_size,
                              hipStream_t stream) {
  const float* x  = (const float*)d_in[0];
  const float* Wq = (const float*)d_in[1];
  const float* bq = (const float*)d_in[2];
  const float* Wk = (const float*)d_in[3];
  const float* bk = (const float*)d_in[4];
  const float* Wv = (const float*)d_in[5];
  const float* bv = (const float*)d_in[6];
  float* out = (float*)d_out;

  uint8_t* ws = (uint8_t*)d_ws;
  const size_t XB = 0;
  const size_t WT = XB + (size_t)MTOT * HIDDEN * 2;        // 16 MB
  const size_t QB = WT + (size_t)3 * HIDDEN * HIDDEN * 2;  // +6 MB
  const size_t KB = QB + (size_t)MTOT * HIDDEN * 2;
  const size_t VB = KB + (size_t)MTOT * HIDDEN * 2;        // total ~70 MB
  uint16_t* Xb = (uint16_t*)(ws + XB);
  uint16_t* Wt = (uint16_t*)(ws + WT);
  uint16_t* Qb = (uint16_t*)(ws + QB);
  uint16_t* Kb = (uint16_t*)(ws + KB);
  uint16_t* Vb = (uint16_t*)(ws + VB);   // V^T [64][64][2048]

  cvt_x_kernel<<<dim3(MTOT * HIDDEN / 8 / 256), 256, 0, stream>>>(x, Xb,
                                                                  MTOT * HIDDEN / 8);
  cvt_w_kernel<<<dim3(16, 16, 3), 256, 0, stream>>>(Wq, Wk, Wv, Wt);
  gemm_qkv_kernel<<<dim3(64, 8, 3), 256, 0, stream>>>(Xb, Wt, bq, bk, bv, Qb, Kb, Vb);
  attn_kernel<<<dim3(2048), 256, 0, stream>>>(Qb, Kb, Vb, out);
}

// Round 4
// 294.354 us; speedup vs baseline: 2.1287x; 1.3282x over previous
//
#include <hip/hip_runtime.h>
#include <hip/hip_bf16.h>
#include <cstdint>

#define HIDDEN 1024
#define HEADS 16
#define HDIM 64
#define BATCH 4
#define SEQ 2048
#define MTOT (BATCH * SEQ)   // 8192

typedef __attribute__((ext_vector_type(8))) short bfrag;   // 8 bf16 (A/B frag)
typedef __attribute__((ext_vector_type(4))) float cfrag;   // 4 f32 (C/D frag)
typedef __attribute__((ext_vector_type(4))) float float4v;
typedef __attribute__((ext_vector_type(4))) unsigned short ushort4v;
typedef __attribute__((ext_vector_type(2))) unsigned int uint2v;

#define AS1 __attribute__((address_space(1)))
#define AS3 __attribute__((address_space(3)))

__device__ __forceinline__ void gl_lds16(const void* g, void* l) {
  // async global->LDS, 16B per lane; LDS dest = wave-uniform base + lane*16
  __builtin_amdgcn_global_load_lds((AS1 void*)g, (AS3 void*)l, 16, 0, 0);
}

__device__ __forceinline__ uint16_t f2b(float f) {  // f32 -> bf16 bits, RNE
  union { float f; uint32_t u; } v; v.f = f;
  uint32_t u = v.u;
  return (uint16_t)((u + 0x7FFFu + ((u >> 16) & 1u)) >> 16);
}

// ---------------- kernel 1: x fp32 -> bf16 ----------------
__global__ __launch_bounds__(256) void cvt_x_kernel(const float* __restrict__ in,
                                                    uint16_t* __restrict__ out, int n8) {
  int i = blockIdx.x * blockDim.x + threadIdx.x;
  if (i >= n8) return;
  float4v a = ((const float4v*)in)[2 * i];
  float4v b = ((const float4v*)in)[2 * i + 1];
  bfrag o;
  o[0] = (short)f2b(a[0]); o[1] = (short)f2b(a[1]);
  o[2] = (short)f2b(a[2]); o[3] = (short)f2b(a[3]);
  o[4] = (short)f2b(b[0]); o[5] = (short)f2b(b[1]);
  o[6] = (short)f2b(b[2]); o[7] = (short)f2b(b[3]);
  ((bfrag*)out)[i] = o;
}

// ---------------- kernel 2: W [K][N] fp32 -> Wt [N][K] bf16 (x3) ----------------
__global__ __launch_bounds__(256) void cvt_w_kernel(const float* __restrict__ W0,
                                                    const float* __restrict__ W1,
                                                    const float* __restrict__ W2,
                                                    uint16_t* __restrict__ Wt) {
  const float* W = blockIdx.z == 0 ? W0 : (blockIdx.z == 1 ? W1 : W2);
  uint16_t* out = Wt + (size_t)blockIdx.z * HIDDEN * HIDDEN;
  __shared__ float tile[64][65];
  int n0 = blockIdx.x * 64, k0 = blockIdx.y * 64;
  int t = threadIdx.x;
  int r = t >> 2, cq = (t & 3) * 16;
#pragma unroll
  for (int i = 0; i < 16; i += 4) {
    float4v v = *(const float4v*)&W[(size_t)(k0 + r) * HIDDEN + n0 + cq + i];
    tile[r][cq + i + 0] = v[0]; tile[r][cq + i + 1] = v[1];
    tile[r][cq + i + 2] = v[2]; tile[r][cq + i + 3] = v[3];
  }
  __syncthreads();
  bfrag o0, o1;
#pragma unroll
  for (int i = 0; i < 8; ++i) o0[i] = (short)f2b(tile[cq + i][r]);
#pragma unroll
  for (int i = 0; i < 8; ++i) o1[i] = (short)f2b(tile[cq + 8 + i][r]);
  *(bfrag*)&out[(size_t)(n0 + r) * HIDDEN + k0 + cq] = o0;
  *(bfrag*)&out[(size_t)(n0 + r) * HIDDEN + k0 + cq + 8] = o1;
}

// ---------------- kernel 3: QKV projection GEMM (m97 structure) ----------------
// C[m][n] = sum_k X[m][k] * Wt[n][k] + bias[n]
// which==0: Q bf16 [8192][1024], scaled by 0.125 (softmax scale folded in)
// which==1: K bf16 [8192][1024]
// which==2: V^T bf16 [64 bh][64 d][2048 s]
__global__ __launch_bounds__(256) void gemm_qkv_kernel(
    const uint16_t* __restrict__ X, const uint16_t* __restrict__ Wt,
    const float* __restrict__ b0, const float* __restrict__ b1,
    const float* __restrict__ b2,
    uint16_t* __restrict__ Qo, uint16_t* __restrict__ Ko, uint16_t* __restrict__ Vo) {
  __shared__ uint16_t As[128 * 32];
  __shared__ uint16_t Bs[128 * 32];
  int which = blockIdx.z;
  const uint16_t* Wp = Wt + (size_t)which * HIDDEN * HIDDEN;
  const float* bias = which == 0 ? b0 : (which == 1 ? b1 : b2);

  int m0 = blockIdx.x * 128, n0 = blockIdx.y * 128;
  int tid = threadIdx.x;
  int wave = tid >> 6, lane = tid & 63;
  int wm = wave >> 1, wn = wave & 1;       // 2x2 wave grid, 64x64 per wave
  int g = lane >> 4, c = lane & 15;
  int sr = lane >> 2;                       // staging: row within 16-row chunk
  int sc = (lane & 3) * 8;                  // staging: k offset (8 bf16 = 16B)

  cfrag acc[4][4];
#pragma unroll
  for (int i = 0; i < 4; ++i)
#pragma unroll
    for (int j = 0; j < 4; ++j) acc[i][j] = cfrag{0.f, 0.f, 0.f, 0.f};

  for (int kt = 0; kt < HIDDEN / 32; ++kt) {
    int kc = kt * 32 + sc;
#pragma unroll
    for (int i = 0; i < 2; ++i) {
      int rowA = (i * 4 + wave) * 16;  // wave-uniform
      gl_lds16(&X[(size_t)(m0 + rowA + sr) * HIDDEN + kc], &As[rowA * 32]);
      gl_lds16(&Wp[(size_t)(n0 + rowA + sr) * HIDDEN + kc], &Bs[rowA * 32]);
    }
    __syncthreads();  // vmcnt(0) drained before barrier -> LDS ready
    bfrag af[4], bf[4];
#pragma unroll
    for (int mt = 0; mt < 4; ++mt)
      af[mt] = *(const bfrag*)&As[(wm * 64 + mt * 16 + c) * 32 + g * 8];
#pragma unroll
    for (int nt = 0; nt < 4; ++nt)
      bf[nt] = *(const bfrag*)&Bs[(wn * 64 + nt * 16 + c) * 32 + g * 8];
#pragma unroll
    for (int mt = 0; mt < 4; ++mt)
#pragma unroll
      for (int nt = 0; nt < 4; ++nt)
        acc[mt][nt] = __builtin_amdgcn_mfma_f32_16x16x32_bf16(af[mt], bf[nt],
                                                              acc[mt][nt], 0, 0, 0);
    __syncthreads();  // all waves done with LDS before next stage
  }

  if (which == 2) {
    // V^T epilogue: [bh][d][s]; 4 consecutive s per fragment -> ushort4 store
    int bb_ = m0 >> 11;                 // batch (m0 128-aligned, 2048%128==0)
    int s0 = (m0 & 2047) + wm * 64;
#pragma unroll
    for (int nt = 0; nt < 4; ++nt) {
      int n = n0 + wn * 64 + nt * 16 + c;
      int h = n >> 6, d = n & 63;
      float bb = bias[n];
      size_t base = ((size_t)(bb_ * 16 + h) * 64 + d) * SEQ;
#pragma unroll
      for (int mt = 0; mt < 4; ++mt) {
        int s = s0 + mt * 16 + g * 4;
        ushort4v pk;
        pk[0] = f2b(acc[mt][nt][0] + bb);
        pk[1] = f2b(acc[mt][nt][1] + bb);
        pk[2] = f2b(acc[mt][nt][2] + bb);
        pk[3] = f2b(acc[mt][nt][3] + bb);
        *(ushort4v*)&Vo[base + s] = pk;
      }
    }
  } else {
    uint16_t* out = which == 0 ? Qo : Ko;
    float sc_ = which == 0 ? 0.125f : 1.0f;   // softmax 1/sqrt(64) folded into Q
#pragma unroll
    for (int nt = 0; nt < 4; ++nt) {
      int n = n0 + wn * 64 + nt * 16 + c;
      float bb = bias[n];
#pragma unroll
      for (int mt = 0; mt < 4; ++mt) {
        int mb = m0 + wm * 64 + mt * 16 + g * 4;
#pragma unroll
        for (int r = 0; r < 4; ++r)
          out[(size_t)(mb + r) * HIDDEN + n] = f2b((acc[mt][nt][r] + bb) * sc_);
      }
    }
  }
}

// ---------------- kernel 4: flash attention (transposed in-lane softmax) ----------------
// Q,K bf16 [8192][1024]; VT bf16 [64][64][2048]; out fp32 [8192][1024]
// Whole pipeline runs transposed: S^T = mfma(K,Q), ctx^T = mfma(V^T,P).
// Lane owns q-row q=c: softmax reduce = in-lane tree + 2 shfl_xor (g-groups).
__global__ __launch_bounds__(256, 4) void attn_kernel(
    const uint16_t* __restrict__ Q, const uint16_t* __restrict__ K,
    const uint16_t* __restrict__ VT, float* __restrict__ out) {
  __shared__ uint16_t Ks[2][64 * 64];    // K tile, XOR-swizzled content
  __shared__ uint16_t Vs[2][64 * 64];    // V^T tile [d][s], XOR-swizzled content
  __shared__ __align__(16) uint16_t Pl[4][16][64];  // per-wave P [q][kv], XOR-swz

  // XCD-aware swizzle: each XCD's resident blocks cover 8 heads (KV=4MB=L2)
  int bid = blockIdx.x;
  int wg = (bid & 7) * 256 + (bid >> 3);
  int bh = wg >> 5, qt = wg & 31;
  int b = bh >> 4, h = bh & 15;
  int tid = threadIdx.x, wave = tid >> 6, lane = tid & 63;
  int g = lane >> 4, c = lane & 15;
  size_t rowb = (size_t)b * SEQ;
  int colb = h * HDIM;
  const uint16_t* Kh = K + rowb * HIDDEN + colb;          // [s][d] stride 1024
  const uint16_t* Vh = VT + (size_t)bh * HDIM * SEQ;      // [d][s] stride 2048

  // staging: lane covers 16B; pre-swizzled global col so the LINEAR
  // global_load_lds write lands XOR-swizzled (rule #21 both-sides)
  int r8 = lane >> 3, c8 = lane & 7;
  int scol = ((c8 ^ r8) << 3);           // element offset 0..56
  int sbrow = (wave & 1) * 32;           // this wave's 4 calls start here

  // Q fragment (B-operand now: col=lane&15=q, k = g*8..); same load as before
  int qrow = qt * 64 + wave * 16 + c;
  bfrag aq[2];
  aq[0] = *(const bfrag*)&Q[(rowb + qrow) * HIDDEN + colb + g * 8];
  aq[1] = *(const bfrag*)&Q[(rowb + qrow) * HIDDEN + colb + 32 + g * 8];

  float mr = -INFINITY, lr = 0.f;        // per-lane state for q=c
  cfrag oacc[4];                         // ctx^T: d = dt*16+g*4+r, q = c
#pragma unroll
  for (int dt = 0; dt < 4; ++dt) oacc[dt] = cfrag{0.f, 0.f, 0.f, 0.f};

  // prologue: stage tile 0 into buf 0 (waves 0-1: K rows, waves 2-3: V rows)
  if (wave < 2) {
#pragma unroll
    for (int j = 0; j < 4; ++j) {
      int rl = sbrow + j * 8;
      gl_lds16(&Kh[(size_t)(rl + r8) * HIDDEN + scol], &Ks[0][rl * 64]);
    }
  } else {
#pragma unroll
    for (int j = 0; j < 4; ++j) {
      int rl = sbrow + j * 8;
      gl_lds16(&Vh[(size_t)(rl + r8) * SEQ + scol], &Vs[0][rl * 64]);
    }
  }
  __syncthreads();  // compiler drains vmcnt before barrier -> tile 0 ready

  int cur = 0;
  int sw = (c & 7) << 4;                 // read-side byte swizzle (K/V and P)
  uint8_t* Pb = (uint8_t*)Pl + wave * 2048 + c * 128;  // this lane's P row

  for (int t = 0; t < 32; ++t) {
    int j0 = t * 64;
    // issue next-tile stage first; latency hides under this tile's compute
    if (t < 31) {
      int jn = j0 + 64;
      if (wave < 2) {
#pragma unroll
        for (int j = 0; j < 4; ++j) {
          int rl = sbrow + j * 8;
          gl_lds16(&Kh[(size_t)(jn + rl + r8) * HIDDEN + scol],
                   &Ks[cur ^ 1][rl * 64]);
        }
      } else {
#pragma unroll
        for (int j = 0; j < 4; ++j) {
          int rl = sbrow + j * 8;
          gl_lds16(&Vh[(size_t)(rl + r8) * SEQ + jn + scol],
                   &Vs[cur ^ 1][rl * 64]);
        }
      }
    }

    const uint8_t* Kbuf = (const uint8_t*)Ks[cur];
    const uint8_t* Vbuf = (const uint8_t*)Vs[cur];

    // S^T = K @ Q^T from swizzled LDS; lane holds kv = nt*16+g*4+r, q = c
    cfrag s[4];
#pragma unroll
    for (int nt = 0; nt < 4; ++nt) s[nt] = cfrag{0.f, 0.f, 0.f, 0.f};
    __builtin_amdgcn_s_setprio(1);
#pragma unroll
    for (int kb = 0; kb < 2; ++kb) {
#pragma unroll
      for (int nt = 0; nt < 4; ++nt) {
        int off = ((nt * 16 + c) * 128 + kb * 64 + g * 16) ^ sw;
        bfrag bk = *(const bfrag*)(Kbuf + off);
        s[nt] = __builtin_amdgcn_mfma_f32_16x16x32_bf16(bk, aq[kb], s[nt], 0, 0, 0);
      }
    }
    __builtin_amdgcn_s_setprio(0);

    // online softmax, in-lane over 16 kv values + 2 cross-g shfls
    float mx = fmaxf(fmaxf(s[0][0], s[0][1]), fmaxf(s[0][2], s[0][3]));
#pragma unroll
    for (int nt = 1; nt < 4; ++nt)
      mx = fmaxf(mx, fmaxf(fmaxf(s[nt][0], s[nt][1]), fmaxf(s[nt][2], s[nt][3])));
    mx = fmaxf(mx, __shfl_xor(mx, 16, 64));
    mx = fmaxf(mx, __shfl_xor(mx, 32, 64));   // mx uniform across g-quartet
    if (mx > mr + 8.0f) {                     // defer-max (T13): rescale only
      float alpha = __expf(mr - mx);          // when max grows > THR
      lr *= alpha;
#pragma unroll
      for (int dt = 0; dt < 4; ++dt)
#pragma unroll
        for (int r = 0; r < 4; ++r) oacc[dt][r] *= alpha;
      mr = mx;
    }
    float ps = 0.f;
#pragma unroll
    for (int nt = 0; nt < 4; ++nt) {
#pragma unroll
      for (int r = 0; r < 4; ++r) s[nt][r] = __expf(s[nt][r] - mr);
      ps += (s[nt][0] + s[nt][1]) + (s[nt][2] + s[nt][3]);
    }
    ps += __shfl_xor(ps, 16, 64);
    ps += __shfl_xor(ps, 32, 64);
    lr += ps;

    // pack P -> bf16 pairs (T12 cvt_pk) and store 8B per nt, XOR-swizzled
#pragma unroll
    for (int nt = 0; nt < 4; ++nt) {
      uint32_t w0, w1;
      asm("v_cvt_pk_bf16_f32 %0, %1, %2" : "=v"(w0) : "v"(s[nt][0]), "v"(s[nt][1]));
      asm("v_cvt_pk_bf16_f32 %0, %1, %2" : "=v"(w1) : "v"(s[nt][2]), "v"(s[nt][3]));
      uint2v pw; pw[0] = w0; pw[1] = w1;
      *(uint2v*)(Pb + ((nt * 32 + g * 8) ^ sw)) = pw;
    }
    // in-wave only: make P writes visible before fragment reads (rule #18)
    asm volatile("s_waitcnt lgkmcnt(0)" ::: "memory");
    __builtin_amdgcn_sched_barrier(0);

    // PV transposed: ctx^T += V^T @ P^T; A = V^T rows, B = P rows (q=c)
    __builtin_amdgcn_s_setprio(1);
#pragma unroll
    for (int kb = 0; kb < 2; ++kb) {
      bfrag ap = *(const bfrag*)(Pb + ((kb * 64 + g * 16) ^ sw));
#pragma unroll
      for (int dt = 0; dt < 4; ++dt) {
        int off = ((dt * 16 + c) * 128 + kb * 64 + g * 16) ^ sw;
        bfrag bv = *(const bfrag*)(Vbuf + off);
        oacc[dt] = __builtin_amdgcn_mfma_f32_16x16x32_bf16(bv, ap, oacc[dt], 0, 0, 0);
      }
    }
    __builtin_amdgcn_s_setprio(0);

    __syncthreads();  // drains this wave's stage vmcnt; next tile ready
    cur ^= 1;
  }

  // epilogue: lane writes q-row c, cols d = dt*16+g*4..+3 -> contiguous float4
  float inv = 1.0f / lr;
  size_t orow = rowb + (size_t)qt * 64 + wave * 16 + c;
#pragma unroll
  for (int dt = 0; dt < 4; ++dt) {
    float4v o;
    o[0] = oacc[dt][0] * inv; o[1] = oacc[dt][1] * inv;
    o[2] = oacc[dt][2] * inv; o[3] = oacc[dt][3] * inv;
    *(float4v*)&out[orow * HIDDEN + colb + dt * 16 + g * 4] = o;
  }
}

extern "C" void kernel_launch(void* const* d_in, const int* in_sizes, int n_in,
                              void* d_out, int out_size, void* d_ws, size_t ws_size,
                              hipStream_t stream) {
  const float* x  = (const float*)d_in[0];
  const float* Wq = (const float*)d_in[1];
  const float* bq = (const float*)d_in[2];
  const float* Wk = (const float*)d_in[3];
  const float* bk = (const float*)d_in[4];
  const float* Wv = (const float*)d_in[5];
  const float* bv = (const float*)d_in[6];
  float* out = (float*)d_out;

  uint8_t* ws = (uint8_t*)d_ws;
  const size_t XB = 0;
  const size_t WT = XB + (size_t)MTOT * HIDDEN * 2;        // 16 MB
  const size_t QB = WT + (size_t)3 * HIDDEN * HIDDEN * 2;  // +6 MB
  const size_t KB = QB + (size_t)MTOT * HIDDEN * 2;
  const size_t VB = KB + (size_t)MTOT * HIDDEN * 2;        // total ~70 MB
  uint16_t* Xb = (uint16_t*)(ws + XB);
  uint16_t* Wt = (uint16_t*)(ws + WT);
  uint16_t* Qb = (uint16_t*)(ws + QB);
  uint16_t* Kb = (uint16_t*)(ws + KB);
  uint16_t* Vb = (uint16_t*)(ws + VB);   // V^T [64][64][2048]

  cvt_x_kernel<<<dim3(MTOT * HIDDEN / 8 / 256), 256, 0, stream>>>(x, Xb,
                                                                  MTOT * HIDDEN / 8);
  cvt_w_kernel<<<dim3(16, 16, 3), 256, 0, stream>>>(Wq, Wk, Wv, Wt);
  gemm_qkv_kernel<<<dim3(64, 8, 3), 256, 0, stream>>>(Xb, Wt, bq, bk, bv, Qb, Kb, Vb);
  attn_kernel<<<dim3(2048), 256, 0, stream>>>(Qb, Kb, Vb, out);
}

// Round 5
// 276.983 us; speedup vs baseline: 2.2622x; 1.0627x over previous
//
#include <hip/hip_runtime.h>
#include <hip/hip_bf16.h>
#include <cstdint>

#define HIDDEN 1024
#define HEADS 16
#define HDIM 64
#define BATCH 4
#define SEQ 2048
#define MTOT (BATCH * SEQ)   // 8192

typedef __attribute__((ext_vector_type(8))) short bfrag;   // 8 bf16 (A/B frag)
typedef __attribute__((ext_vector_type(4))) float cfrag;   // 4 f32 (C/D frag)
typedef __attribute__((ext_vector_type(4))) float float4v;
typedef __attribute__((ext_vector_type(4))) unsigned short ushort4v;
typedef __attribute__((ext_vector_type(2))) unsigned int uint2v;

#define AS1 __attribute__((address_space(1)))
#define AS3 __attribute__((address_space(3)))

__device__ __forceinline__ void gl_lds16(const void* g, void* l) {
  // async global->LDS, 16B per lane; LDS dest = wave-uniform base + lane*16
  __builtin_amdgcn_global_load_lds((AS1 void*)g, (AS3 void*)l, 16, 0, 0);
}

__device__ __forceinline__ uint16_t f2b(float f) {  // f32 -> bf16 bits, RNE
  union { float f; uint32_t u; } v; v.f = f;
  uint32_t u = v.u;
  return (uint16_t)((u + 0x7FFFu + ((u >> 16) & 1u)) >> 16);
}

// ---------------- kernel 1: x fp32 -> bf16 ----------------
__global__ __launch_bounds__(256) void cvt_x_kernel(const float* __restrict__ in,
                                                    uint16_t* __restrict__ out, int n8) {
  int i = blockIdx.x * blockDim.x + threadIdx.x;
  if (i >= n8) return;
  float4v a = ((const float4v*)in)[2 * i];
  float4v b = ((const float4v*)in)[2 * i + 1];
  bfrag o;
  o[0] = (short)f2b(a[0]); o[1] = (short)f2b(a[1]);
  o[2] = (short)f2b(a[2]); o[3] = (short)f2b(a[3]);
  o[4] = (short)f2b(b[0]); o[5] = (short)f2b(b[1]);
  o[6] = (short)f2b(b[2]); o[7] = (short)f2b(b[3]);
  ((bfrag*)out)[i] = o;
}

// ---------------- kernel 2: W [K][N] fp32 -> Wt [N][K] bf16 (x3) ----------------
__global__ __launch_bounds__(256) void cvt_w_kernel(const float* __restrict__ W0,
                                                    const float* __restrict__ W1,
                                                    const float* __restrict__ W2,
                                                    uint16_t* __restrict__ Wt) {
  const float* W = blockIdx.z == 0 ? W0 : (blockIdx.z == 1 ? W1 : W2);
  uint16_t* out = Wt + (size_t)blockIdx.z * HIDDEN * HIDDEN;
  __shared__ float tile[64][65];
  int n0 = blockIdx.x * 64, k0 = blockIdx.y * 64;
  int t = threadIdx.x;
  int r = t >> 2, cq = (t & 3) * 16;
#pragma unroll
  for (int i = 0; i < 16; i += 4) {
    float4v v = *(const float4v*)&W[(size_t)(k0 + r) * HIDDEN + n0 + cq + i];
    tile[r][cq + i + 0] = v[0]; tile[r][cq + i + 1] = v[1];
    tile[r][cq + i + 2] = v[2]; tile[r][cq + i + 3] = v[3];
  }
  __syncthreads();
  bfrag o0, o1;
#pragma unroll
  for (int i = 0; i < 8; ++i) o0[i] = (short)f2b(tile[cq + i][r]);
#pragma unroll
  for (int i = 0; i < 8; ++i) o1[i] = (short)f2b(tile[cq + 8 + i][r]);
  *(bfrag*)&out[(size_t)(n0 + r) * HIDDEN + k0 + cq] = o0;
  *(bfrag*)&out[(size_t)(n0 + r) * HIDDEN + k0 + cq + 8] = o1;
}

// ---------------- kernel 3: QKV projection GEMM (m97 structure, XCD-chunked) --
// C[m][n] = sum_k X[m][k] * Wt[n][k] + bias[n]
// which==0: Q bf16 [8192][1024], scaled by 0.125*log2(e) (exp2-domain softmax)
// which==1: K bf16 [8192][1024]
// which==2: V^T bf16 [64 bh][64 d][2048 s]
__global__ __launch_bounds__(256) void gemm_qkv_kernel(
    const uint16_t* __restrict__ X, const uint16_t* __restrict__ Wt,
    const float* __restrict__ b0, const float* __restrict__ b1,
    const float* __restrict__ b2,
    uint16_t* __restrict__ Qo, uint16_t* __restrict__ Ko, uint16_t* __restrict__ Vo) {
  __shared__ uint16_t As[128 * 32];
  __shared__ uint16_t Bs[128 * 32];

  // XCD-chunked decomposition: 1536 blocks = 8 XCDs x (3 which x 8 m x 8 n).
  // Per-XCD phase working set = X-panel (2MB) + one W (2MB) = one L2.
  int id = blockIdx.x;
  int xcd = id & 7, j = id >> 3;        // j in 0..191
  int which = j >> 6;                    // 0..2, phases of 64
  int r_ = j & 63;
  int m0 = (xcd * 8 + (r_ >> 3)) * 128;
  int n0 = (r_ & 7) * 128;

  const uint16_t* Wp = Wt + (size_t)which * HIDDEN * HIDDEN;
  const float* bias = which == 0 ? b0 : (which == 1 ? b1 : b2);

  int tid = threadIdx.x;
  int wave = tid >> 6, lane = tid & 63;
  int wm = wave >> 1, wn = wave & 1;       // 2x2 wave grid, 64x64 per wave
  int g = lane >> 4, c = lane & 15;
  int sr = lane >> 2;                       // staging: row within 16-row chunk
  int sc = (lane & 3) * 8;                  // staging: k offset (8 bf16 = 16B)

  cfrag acc[4][4];
#pragma unroll
  for (int i = 0; i < 4; ++i)
#pragma unroll
    for (int jj = 0; jj < 4; ++jj) acc[i][jj] = cfrag{0.f, 0.f, 0.f, 0.f};

  for (int kt = 0; kt < HIDDEN / 32; ++kt) {
    int kc = kt * 32 + sc;
#pragma unroll
    for (int i = 0; i < 2; ++i) {
      int rowA = (i * 4 + wave) * 16;  // wave-uniform
      gl_lds16(&X[(size_t)(m0 + rowA + sr) * HIDDEN + kc], &As[rowA * 32]);
      gl_lds16(&Wp[(size_t)(n0 + rowA + sr) * HIDDEN + kc], &Bs[rowA * 32]);
    }
    __syncthreads();  // vmcnt(0) drained before barrier -> LDS ready
    bfrag af[4], bf[4];
#pragma unroll
    for (int mt = 0; mt < 4; ++mt)
      af[mt] = *(const bfrag*)&As[(wm * 64 + mt * 16 + c) * 32 + g * 8];
#pragma unroll
    for (int nt = 0; nt < 4; ++nt)
      bf[nt] = *(const bfrag*)&Bs[(wn * 64 + nt * 16 + c) * 32 + g * 8];
#pragma unroll
    for (int mt = 0; mt < 4; ++mt)
#pragma unroll
      for (int nt = 0; nt < 4; ++nt)
        acc[mt][nt] = __builtin_amdgcn_mfma_f32_16x16x32_bf16(af[mt], bf[nt],
                                                              acc[mt][nt], 0, 0, 0);
    __syncthreads();  // all waves done with LDS before next stage
  }

  if (which == 2) {
    // V^T epilogue: [bh][d][s]; 4 consecutive s per fragment -> ushort4 store
    int bb_ = m0 >> 11;                 // batch (m0 128-aligned, 2048%128==0)
    int s0 = (m0 & 2047) + wm * 64;
#pragma unroll
    for (int nt = 0; nt < 4; ++nt) {
      int n = n0 + wn * 64 + nt * 16 + c;
      int h = n >> 6, d = n & 63;
      float bb = bias[n];
      size_t base = ((size_t)(bb_ * 16 + h) * 64 + d) * SEQ;
#pragma unroll
      for (int mt = 0; mt < 4; ++mt) {
        int s = s0 + mt * 16 + g * 4;
        ushort4v pk;
        pk[0] = f2b(acc[mt][nt][0] + bb);
        pk[1] = f2b(acc[mt][nt][1] + bb);
        pk[2] = f2b(acc[mt][nt][2] + bb);
        pk[3] = f2b(acc[mt][nt][3] + bb);
        *(ushort4v*)&Vo[base + s] = pk;
      }
    }
  } else {
    uint16_t* out = which == 0 ? Qo : Ko;
    // Q: fold softmax scale AND log2(e) so scores arrive in exp2 domain
    float sc_ = which == 0 ? 0.125f * 1.44269504088896f : 1.0f;
#pragma unroll
    for (int nt = 0; nt < 4; ++nt) {
      int n = n0 + wn * 64 + nt * 16 + c;
      float bb = bias[n];
#pragma unroll
      for (int mt = 0; mt < 4; ++mt) {
        int mb = m0 + wm * 64 + mt * 16 + g * 4;
#pragma unroll
        for (int r = 0; r < 4; ++r)
          out[(size_t)(mb + r) * HIDDEN + n] = f2b((acc[mt][nt][r] + bb) * sc_);
      }
    }
  }
}

// ---------------- kernel 4: flash attention (transposed, exp2, no fences) ----
// Q,K bf16 [8192][1024]; VT bf16 [64][64][2048]; out fp32 [8192][1024]
// S^T = mfma(K,Q) in log2 domain; ctx^T = mfma(V^T,P). Lane owns q-row q=c.
__global__ __launch_bounds__(256, 4) void attn_kernel(
    const uint16_t* __restrict__ Q, const uint16_t* __restrict__ K,
    const uint16_t* __restrict__ VT, float* __restrict__ out) {
  __shared__ uint16_t Ks[2][64 * 64];    // K tile, XOR-swizzled content
  __shared__ uint16_t Vs[2][64 * 64];    // V^T tile [d][s], XOR-swizzled content
  __shared__ __align__(16) uint16_t Pl[4][16][64];  // per-wave P [q][kv], XOR-swz

  // XCD-aware swizzle: each XCD's resident blocks cover 8 heads (KV=4MB=L2)
  int bid = blockIdx.x;
  int wg = (bid & 7) * 256 + (bid >> 3);
  int bh = wg >> 5, qt = wg & 31;
  int b = bh >> 4, h = bh & 15;
  int tid = threadIdx.x, wave = tid >> 6, lane = tid & 63;
  int g = lane >> 4, c = lane & 15;
  size_t rowb = (size_t)b * SEQ;
  int colb = h * HDIM;
  const uint16_t* Kh = K + rowb * HIDDEN + colb;          // [s][d] stride 1024
  const uint16_t* Vh = VT + (size_t)bh * HDIM * SEQ;      // [d][s] stride 2048

  // staging: lane covers 16B; pre-swizzled global col so the LINEAR
  // global_load_lds write lands XOR-swizzled (rule #21 both-sides)
  int r8 = lane >> 3, c8 = lane & 7;
  int scol = ((c8 ^ r8) << 3);           // element offset 0..56
  int sbrow = (wave & 1) * 32;           // this wave's 4 calls start here

  // Q fragment (B-operand: col=lane&15=q, k = g*8..)
  int qrow = qt * 64 + wave * 16 + c;
  bfrag aq[2];
  aq[0] = *(const bfrag*)&Q[(rowb + qrow) * HIDDEN + colb + g * 8];
  aq[1] = *(const bfrag*)&Q[(rowb + qrow) * HIDDEN + colb + 32 + g * 8];

  float mr = -INFINITY, lr = 0.f;        // per-lane state; lr = PARTIAL row sum
  cfrag oacc[4];                         // ctx^T: d = dt*16+g*4+r, q = c
#pragma unroll
  for (int dt = 0; dt < 4; ++dt) oacc[dt] = cfrag{0.f, 0.f, 0.f, 0.f};

  // prologue: stage tile 0 into buf 0 (waves 0-1: K rows, waves 2-3: V rows)
  if (wave < 2) {
#pragma unroll
    for (int j = 0; j < 4; ++j) {
      int rl = sbrow + j * 8;
      gl_lds16(&Kh[(size_t)(rl + r8) * HIDDEN + scol], &Ks[0][rl * 64]);
    }
  } else {
#pragma unroll
    for (int j = 0; j < 4; ++j) {
      int rl = sbrow + j * 8;
      gl_lds16(&Vh[(size_t)(rl + r8) * SEQ + scol], &Vs[0][rl * 64]);
    }
  }
  __syncthreads();  // compiler drains vmcnt before barrier -> tile 0 ready

  int cur = 0;
  int sw = (c & 7) << 4;                 // read-side byte swizzle (K/V and P)
  uint8_t* Pb = (uint8_t*)Pl + wave * 2048 + c * 128;  // this lane's P row

  for (int t = 0; t < 32; ++t) {
    int j0 = t * 64;
    // issue next-tile stage first; latency hides under this tile's compute
    if (t < 31) {
      int jn = j0 + 64;
      if (wave < 2) {
#pragma unroll
        for (int j = 0; j < 4; ++j) {
          int rl = sbrow + j * 8;
          gl_lds16(&Kh[(size_t)(jn + rl + r8) * HIDDEN + scol],
                   &Ks[cur ^ 1][rl * 64]);
        }
      } else {
#pragma unroll
        for (int j = 0; j < 4; ++j) {
          int rl = sbrow + j * 8;
          gl_lds16(&Vh[(size_t)(rl + r8) * SEQ + jn + scol],
                   &Vs[cur ^ 1][rl * 64]);
        }
      }
    }

    const uint8_t* Kbuf = (const uint8_t*)Ks[cur];
    const uint8_t* Vbuf = (const uint8_t*)Vs[cur];

    // S^T = K @ Q^T from swizzled LDS; lane holds kv = nt*16+g*4+r, q = c
    cfrag s[4];
#pragma unroll
    for (int nt = 0; nt < 4; ++nt) s[nt] = cfrag{0.f, 0.f, 0.f, 0.f};
    __builtin_amdgcn_s_setprio(1);
#pragma unroll
    for (int kb = 0; kb < 2; ++kb) {
#pragma unroll
      for (int nt = 0; nt < 4; ++nt) {
        int off = ((nt * 16 + c) * 128 + kb * 64 + g * 16) ^ sw;
        bfrag bk = *(const bfrag*)(Kbuf + off);
        s[nt] = __builtin_amdgcn_mfma_f32_16x16x32_bf16(bk, aq[kb], s[nt], 0, 0, 0);
      }
    }
    __builtin_amdgcn_s_setprio(0);

    // online softmax (log2 domain), in-lane tree + 2 cross-g shfls (max only)
    float mx = fmaxf(fmaxf(fmaxf(s[0][0], s[0][1]), s[0][2]), s[0][3]);
    float mx1 = fmaxf(fmaxf(fmaxf(s[1][0], s[1][1]), s[1][2]), s[1][3]);
    float mx2 = fmaxf(fmaxf(fmaxf(s[2][0], s[2][1]), s[2][2]), s[2][3]);
    float mx3 = fmaxf(fmaxf(fmaxf(s[3][0], s[3][1]), s[3][2]), s[3][3]);
    mx = fmaxf(fmaxf(mx, mx1), fmaxf(mx2, mx3));
    mx = fmaxf(mx, __shfl_xor(mx, 16, 64));
    mx = fmaxf(mx, __shfl_xor(mx, 32, 64));   // mx uniform across g-quartet
    if (mx > mr + 8.0f) {                     // defer-max (T13), log2 units
      float alpha = __builtin_amdgcn_exp2f(mr - mx);
      lr *= alpha;
#pragma unroll
      for (int dt = 0; dt < 4; ++dt)
#pragma unroll
        for (int r = 0; r < 4; ++r) oacc[dt][r] *= alpha;
      mr = mx;
    }
    float ps = 0.f;
#pragma unroll
    for (int nt = 0; nt < 4; ++nt) {
#pragma unroll
      for (int r = 0; r < 4; ++r)
        s[nt][r] = __builtin_amdgcn_exp2f(s[nt][r] - mr);
      ps += (s[nt][0] + s[nt][1]) + (s[nt][2] + s[nt][3]);
    }
    lr += ps;   // partial (this lane's 16 kv); cross-g reduce at epilogue

    // pack P -> bf16 pairs (T12 cvt_pk) and store 8B per nt, XOR-swizzled
#pragma unroll
    for (int nt = 0; nt < 4; ++nt) {
      uint32_t w0, w1;
      asm("v_cvt_pk_bf16_f32 %0, %1, %2" : "=v"(w0) : "v"(s[nt][0]), "v"(s[nt][1]));
      asm("v_cvt_pk_bf16_f32 %0, %1, %2" : "=v"(w1) : "v"(s[nt][2]), "v"(s[nt][3]));
      uint2v pw; pw[0] = w0; pw[1] = w1;
      *(uint2v*)(Pb + ((nt * 32 + g * 8) ^ sw)) = pw;
    }
    // NOTE: no explicit fence — same-wave DS ops are in-order; compiler
    // inserts the precise lgkmcnt for the may-alias write->read pair.

    // PV transposed: ctx^T += V^T @ P^T; A = V^T rows, B = P rows (q=c)
    __builtin_amdgcn_s_setprio(1);
#pragma unroll
    for (int kb = 0; kb < 2; ++kb) {
      bfrag ap = *(const bfrag*)(Pb + ((kb * 64 + g * 16) ^ sw));
#pragma unroll
      for (int dt = 0; dt < 4; ++dt) {
        int off = ((dt * 16 + c) * 128 + kb * 64 + g * 16) ^ sw;
        bfrag bv = *(const bfrag*)(Vbuf + off);
        oacc[dt] = __builtin_amdgcn_mfma_f32_16x16x32_bf16(bv, ap, oacc[dt], 0, 0, 0);
      }
    }
    __builtin_amdgcn_s_setprio(0);

    __syncthreads();  // drains this wave's stage vmcnt; next tile ready
    cur ^= 1;
  }

  // epilogue: finish l reduction (2 shfls), write q-row c as float4s
  lr += __shfl_xor(lr, 16, 64);
  lr += __shfl_xor(lr, 32, 64);
  float inv = 1.0f / lr;
  size_t orow = rowb + (size_t)qt * 64 + wave * 16 + c;
#pragma unroll
  for (int dt = 0; dt < 4; ++dt) {
    float4v o;
    o[0] = oacc[dt][0] * inv; o[1] = oacc[dt][1] * inv;
    o[2] = oacc[dt][2] * inv; o[3] = oacc[dt][3] * inv;
    *(float4v*)&out[orow * HIDDEN + colb + dt * 16 + g * 4] = o;
  }
}

extern "C" void kernel_launch(void* const* d_in, const int* in_sizes, int n_in,
                              void* d_out, int out_size, void* d_ws, size_t ws_size,
                              hipStream_t stream) {
  const float* x  = (const float*)d_in[0];
  const float* Wq = (const float*)d_in[1];
  const float* bq = (const float*)d_in[2];
  const float* Wk = (const float*)d_in[3];
  const float* bk = (const float*)d_in[4];
  const float* Wv = (const float*)d_in[5];
  const float* bv = (const float*)d_in[6];
  float* out = (float*)d_out;

  uint8_t* ws = (uint8_t*)d_ws;
  const size_t XB = 0;
  const size_t WT = XB + (size_t)MTOT * HIDDEN * 2;        // 16 MB
  const size_t QB = WT + (size_t)3 * HIDDEN * HIDDEN * 2;  // +6 MB
  const size_t KB = QB + (size_t)MTOT * HIDDEN * 2;
  const size_t VB = KB + (size_t)MTOT * HIDDEN * 2;        // total ~70 MB
  uint16_t* Xb = (uint16_t*)(ws + XB);
  uint16_t* Wt = (uint16_t*)(ws + WT);
  uint16_t* Qb = (uint16_t*)(ws + QB);
  uint16_t* Kb = (uint16_t*)(ws + KB);
  uint16_t* Vb = (uint16_t*)(ws + VB);   // V^T [64][64][2048]

  cvt_x_kernel<<<dim3(MTOT * HIDDEN / 8 / 256), 256, 0, stream>>>(x, Xb,
                                                                  MTOT * HIDDEN / 8);
  cvt_w_kernel<<<dim3(16, 16, 3), 256, 0, stream>>>(Wq, Wk, Wv, Wt);
  gemm_qkv_kernel<<<dim3(1536), 256, 0, stream>>>(Xb, Wt, bq, bk, bv, Qb, Kb, Vb);
  attn_kernel<<<dim3(2048), 256, 0, stream>>>(Qb, Kb, Vb, out);
}